// Round 1
// baseline (9238.918 us; speedup 1.0000x reference)
//
#include <hip/hip_runtime.h>
#include <math.h>

#define DMODEL 1024
#define HIDDEN 4096
#define VOCAB  32000
#define NHEAD  16
#define DHEAD  64
#define NLAYER 6
#define BATCH  4
#define SEQ    256
#define SEQE   256

// ---------------- embedding + positional encoding ----------------
__global__ __launch_bounds__(256) void embed_kernel(const int* __restrict__ X,
                                                    const float* __restrict__ emb,
                                                    float* __restrict__ h)
{
    int token = blockIdx.x;           // 0..B*S-1
    int s = token % SEQ;
    int tid = threadIdx.x;
    int xv = X[token];
    const float* erow = emb + (size_t)xv * DMODEL;
    float* hrow = h + (size_t)token * DMODEL;
#pragma unroll
    for (int i = 0; i < 4; i++) {
        int d = tid + i * 256;
        float j = (float)(d & ~1);
        // 1/10000^(j/dm) = exp(-ln(10000)*j/1024)
        float invf = expf(j * (-9.210340371976184f / 1024.0f));
        float ang = (float)s * invf;
        float p = (d & 1) ? cosf(ang) : sinf(ang);
        hrow[d] = erow[d] * 32.0f + p;   // sqrt(1024)=32
    }
}

// ---------------- tiled fp32 GEMM: C = A(MxK) @ B(KxN) (+bias)(+relu) ------
// M,N multiples of 64; K multiple of 16. Row-major everywhere.
template<bool BIAS, bool RELU>
__global__ __launch_bounds__(256) void gemm_kernel(const float* __restrict__ A,
                                                   const float* __restrict__ Bm,
                                                   const float* __restrict__ bias,
                                                   float* __restrict__ C,
                                                   int M, int N, int K)
{
    __shared__ float As[16][68];
    __shared__ float Bs[16][68];
    int tid = threadIdx.x;
    int n0 = blockIdx.x * 64;
    int m0 = blockIdx.y * 64;
    int tm = tid >> 4;          // 0..15
    int tn = tid & 15;          // 0..15
    int la_m = tid >> 2;        // 0..63
    int la_k = (tid & 3) << 2;  // 0,4,8,12
    int lb_k = tid >> 4;        // 0..15
    int lb_n = (tid & 15) << 2; // 0..60

    const float* Aptr = A + (size_t)(m0 + la_m) * K + la_k;
    const float* Bptr = Bm + (size_t)lb_k * N + n0 + lb_n;

    float acc[4][4] = {};

    for (int k0 = 0; k0 < K; k0 += 16) {
        float4 a = *(const float4*)(Aptr + k0);
        float4 b = *(const float4*)(Bptr + (size_t)k0 * N);
        As[la_k + 0][la_m] = a.x;
        As[la_k + 1][la_m] = a.y;
        As[la_k + 2][la_m] = a.z;
        As[la_k + 3][la_m] = a.w;
        *(float4*)&Bs[lb_k][lb_n] = b;
        __syncthreads();
#pragma unroll
        for (int kk = 0; kk < 16; kk++) {
            float4 av = *(const float4*)&As[kk][tm << 2];
            float4 bv = *(const float4*)&Bs[kk][tn << 2];
            acc[0][0] = fmaf(av.x, bv.x, acc[0][0]);
            acc[0][1] = fmaf(av.x, bv.y, acc[0][1]);
            acc[0][2] = fmaf(av.x, bv.z, acc[0][2]);
            acc[0][3] = fmaf(av.x, bv.w, acc[0][3]);
            acc[1][0] = fmaf(av.y, bv.x, acc[1][0]);
            acc[1][1] = fmaf(av.y, bv.y, acc[1][1]);
            acc[1][2] = fmaf(av.y, bv.z, acc[1][2]);
            acc[1][3] = fmaf(av.y, bv.w, acc[1][3]);
            acc[2][0] = fmaf(av.z, bv.x, acc[2][0]);
            acc[2][1] = fmaf(av.z, bv.y, acc[2][1]);
            acc[2][2] = fmaf(av.z, bv.z, acc[2][2]);
            acc[2][3] = fmaf(av.z, bv.w, acc[2][3]);
            acc[3][0] = fmaf(av.w, bv.x, acc[3][0]);
            acc[3][1] = fmaf(av.w, bv.y, acc[3][1]);
            acc[3][2] = fmaf(av.w, bv.z, acc[3][2]);
            acc[3][3] = fmaf(av.w, bv.w, acc[3][3]);
        }
        __syncthreads();
    }

    float4 b4 = make_float4(0.f, 0.f, 0.f, 0.f);
    if (BIAS) b4 = *(const float4*)(bias + n0 + (tn << 2));
#pragma unroll
    for (int i = 0; i < 4; i++) {
        int m = m0 + (tm << 2) + i;
        float4 cv = make_float4(acc[i][0] + b4.x, acc[i][1] + b4.y,
                                acc[i][2] + b4.z, acc[i][3] + b4.w);
        if (RELU) {
            cv.x = fmaxf(cv.x, 0.f); cv.y = fmaxf(cv.y, 0.f);
            cv.z = fmaxf(cv.z, 0.f); cv.w = fmaxf(cv.w, 0.f);
        }
        *(float4*)(C + (size_t)m * N + n0 + (tn << 2)) = cv;
    }
}

// ---------------- fused attention: one wave per (b, head, q-row) -----------
// Q rows: B*Sq tokens, K/V rows: B*Sk tokens, layout (token, DMODEL).
// Masked (ki >= vlim) score = 1e-6 exactly (reference semantics, not -inf).
__global__ __launch_bounds__(64) void attn_kernel(const float* __restrict__ Q,
                                                  const float* __restrict__ K,
                                                  const float* __restrict__ V,
                                                  float* __restrict__ O,
                                                  const int* __restrict__ valid,
                                                  int per_query, int Sk)
{
    int qi = blockIdx.x;
    int hh = blockIdx.y;
    int b  = blockIdx.z;
    int lane = threadIdx.x;   // 64
    __shared__ float qs[DHEAD];
    __shared__ float ws[256];

    const float* qrow = Q + ((size_t)(b * gridDim.x + qi)) * DMODEL + hh * DHEAD;
    qs[lane] = qrow[lane];
    __syncthreads();

    int vl = valid[b];
    int vlim = per_query ? min(vl, qi + 1) : vl;

    float sv[4];
#pragma unroll
    for (int j = 0; j < 4; j++) {
        int ki = lane + j * 64;
        const float* krow = K + ((size_t)(b * Sk + ki)) * DMODEL + hh * DHEAD;
        float acc = 0.f;
#pragma unroll 8
        for (int d = 0; d < DHEAD; d++) acc = fmaf(qs[d], krow[d], acc);
        sv[j] = (ki >= vlim) ? 1e-6f : acc * 0.125f;   // /sqrt(64)
    }
    float m = fmaxf(fmaxf(sv[0], sv[1]), fmaxf(sv[2], sv[3]));
#pragma unroll
    for (int off = 32; off > 0; off >>= 1) m = fmaxf(m, __shfl_xor(m, off));
    float e0 = expf(sv[0] - m), e1 = expf(sv[1] - m);
    float e2 = expf(sv[2] - m), e3 = expf(sv[3] - m);
    float ssum = e0 + e1 + e2 + e3;
#pragma unroll
    for (int off = 32; off > 0; off >>= 1) ssum += __shfl_xor(ssum, off);
    float inv = 1.0f / ssum;
    ws[lane      ] = e0 * inv;
    ws[lane +  64] = e1 * inv;
    ws[lane + 128] = e2 * inv;
    ws[lane + 192] = e3 * inv;
    __syncthreads();

    float acc = 0.f;
    const float* vbase = V + ((size_t)(b * Sk)) * DMODEL + hh * DHEAD + lane;
    for (int k2 = 0; k2 < Sk; k2++)
        acc = fmaf(ws[k2], vbase[(size_t)k2 * DMODEL], acc);
    O[((size_t)(b * gridDim.x + qi)) * DMODEL + hh * DHEAD + lane] = acc;
}

// ---------------- out = LayerNorm(x + r) * g + b, rows of DMODEL -----------
__global__ __launch_bounds__(256) void add_ln_kernel(const float* __restrict__ x,
                                                     const float* __restrict__ r,
                                                     const float* __restrict__ g,
                                                     const float* __restrict__ bb,
                                                     float* __restrict__ out)
{
    int row = blockIdx.x;
    int tid = threadIdx.x;
    const float* xr = x + (size_t)row * DMODEL;
    const float* rr = r + (size_t)row * DMODEL;
    float v[4];
#pragma unroll
    for (int i = 0; i < 4; i++) v[i] = xr[tid + i * 256] + rr[tid + i * 256];

    __shared__ float red[4];
    float s = v[0] + v[1] + v[2] + v[3];
#pragma unroll
    for (int off = 32; off > 0; off >>= 1) s += __shfl_xor(s, off);
    int wid = tid >> 6, lane = tid & 63;
    if (lane == 0) red[wid] = s;
    __syncthreads();
    float mean = (red[0] + red[1] + red[2] + red[3]) * (1.0f / DMODEL);

    float sq = 0.f;
#pragma unroll
    for (int i = 0; i < 4; i++) { float d = v[i] - mean; sq = fmaf(d, d, sq); }
    __syncthreads();   // everyone done reading red before re-writing
#pragma unroll
    for (int off = 32; off > 0; off >>= 1) sq += __shfl_xor(sq, off);
    if (lane == 0) red[wid] = sq;
    __syncthreads();
    float var = (red[0] + red[1] + red[2] + red[3]) * (1.0f / DMODEL);
    float inv = 1.0f / sqrtf(var + 1e-5f);

    float* orow = out + (size_t)row * DMODEL;
#pragma unroll
    for (int i = 0; i < 4; i++) {
        int d = tid + i * 256;
        orow[d] = (v[i] - mean) * inv * g[d] + bb[d];
    }
}

// ---------------------------------------------------------------------------
extern "C" void kernel_launch(void* const* d_in, const int* in_sizes, int n_in,
                              void* d_out, int out_size, void* d_ws, size_t ws_size,
                              hipStream_t stream)
{
    const int*   X         = (const int*)  d_in[0];
    const int*   dec_valid = (const int*)  d_in[1];
    const float* enc       = (const float*)d_in[2];
    const int*   enc_valid = (const int*)  d_in[3];
    const float* emb       = (const float*)d_in[4];
    const float* Wq1  = (const float*)d_in[5];
    const float* Wk1  = (const float*)d_in[6];
    const float* Wv1  = (const float*)d_in[7];
    const float* Wo1  = (const float*)d_in[8];
    const float* Wq2  = (const float*)d_in[9];
    const float* Wk2  = (const float*)d_in[10];
    const float* Wv2  = (const float*)d_in[11];
    const float* Wo2  = (const float*)d_in[12];
    const float* W1   = (const float*)d_in[13];
    const float* W2   = (const float*)d_in[14];
    const float* Wout = (const float*)d_in[15];
    const float* b1   = (const float*)d_in[16];
    const float* b2   = (const float*)d_in[17];
    const float* bout = (const float*)d_in[18];
    const float* ln1g = (const float*)d_in[19];
    const float* ln1b = (const float*)d_in[20];
    const float* ln2g = (const float*)d_in[21];
    const float* ln2b = (const float*)d_in[22];
    const float* ln3g = (const float*)d_in[23];
    const float* ln3b = (const float*)d_in[24];
    float* out = (float*)d_out;
    float* ws  = (float*)d_ws;

    const int MT = BATCH * SEQ;      // 1024 token rows
    const size_t MB = (size_t)1024 * 1024;
    float* h    = ws;
    float* q    = ws + 1 * MB;
    float* k    = ws + 2 * MB;
    float* v    = ws + 3 * MB;
    float* att  = ws + 4 * MB;
    float* ffn  = ws + 1 * MB;       // aliases q..att (4M floats), FFN stage only
    float* proj = ws + 5 * MB;       // also FFN second-gemm output
    float* y    = ws + 6 * MB;
    float* y2   = ws + 7 * MB;

    embed_kernel<<<MT, 256, 0, stream>>>(X, emb, h);

    dim3 g64(DMODEL / 64, MT / 64);
    dim3 ghid(HIDDEN / 64, MT / 64);
    dim3 gvoc(VOCAB / 64, MT / 64);
    dim3 gatt(SEQ, NHEAD, BATCH);

    for (int l = 0; l < NLAYER; l++) {
        const size_t wdd = (size_t)l * DMODEL * DMODEL;
        // ---- self attention ----
        gemm_kernel<false,false><<<g64, 256, 0, stream>>>(h, Wq1 + wdd, nullptr, q, MT, DMODEL, DMODEL);
        gemm_kernel<false,false><<<g64, 256, 0, stream>>>(h, Wk1 + wdd, nullptr, k, MT, DMODEL, DMODEL);
        gemm_kernel<false,false><<<g64, 256, 0, stream>>>(h, Wv1 + wdd, nullptr, v, MT, DMODEL, DMODEL);
        attn_kernel<<<gatt, 64, 0, stream>>>(q, k, v, att, dec_valid, 1, SEQ);
        gemm_kernel<false,false><<<g64, 256, 0, stream>>>(att, Wo1 + wdd, nullptr, proj, MT, DMODEL, DMODEL);
        add_ln_kernel<<<MT, 256, 0, stream>>>(h, proj, ln1g + (size_t)l * DMODEL, ln1b + (size_t)l * DMODEL, y);
        // ---- cross attention ----
        gemm_kernel<false,false><<<g64, 256, 0, stream>>>(y,   Wq2 + wdd, nullptr, q, MT, DMODEL, DMODEL);
        gemm_kernel<false,false><<<g64, 256, 0, stream>>>(enc, Wk2 + wdd, nullptr, k, MT, DMODEL, DMODEL);
        gemm_kernel<false,false><<<g64, 256, 0, stream>>>(enc, Wv2 + wdd, nullptr, v, MT, DMODEL, DMODEL);
        attn_kernel<<<gatt, 64, 0, stream>>>(q, k, v, att, enc_valid, 0, SEQE);
        gemm_kernel<false,false><<<g64, 256, 0, stream>>>(att, Wo2 + wdd, nullptr, proj, MT, DMODEL, DMODEL);
        add_ln_kernel<<<MT, 256, 0, stream>>>(y, proj, ln2g + (size_t)l * DMODEL, ln2b + (size_t)l * DMODEL, y2);
        // ---- FFN ----
        gemm_kernel<true,true ><<<ghid, 256, 0, stream>>>(y2, W1 + (size_t)l * DMODEL * HIDDEN, b1 + (size_t)l * HIDDEN, ffn, MT, HIDDEN, DMODEL);
        gemm_kernel<true,false><<<g64,  256, 0, stream>>>(ffn, W2 + (size_t)l * HIDDEN * DMODEL, b2 + (size_t)l * DMODEL, proj, MT, DMODEL, HIDDEN);
        add_ln_kernel<<<MT, 256, 0, stream>>>(y2, proj, ln3g + (size_t)l * DMODEL, ln3b + (size_t)l * DMODEL, h);
    }

    // ---- final projection into d_out ----
    gemm_kernel<true,false><<<gvoc, 256, 0, stream>>>(h, Wout, bout, out, MT, VOCAB, DMODEL);
}

// Round 2
// 3657.147 us; speedup vs baseline: 2.5263x; 2.5263x over previous
//
#include <hip/hip_runtime.h>
#include <math.h>

#define DMODEL 1024
#define HIDDEN 4096
#define VOCAB  32000
#define NHEAD  16
#define DHEAD  64
#define NLAYER 6
#define BATCH  4
#define SEQ    256

typedef __attribute__((ext_vector_type(8))) short bf16x8;
typedef __attribute__((ext_vector_type(4))) float f32x4;

// round-half-up fp32->bf16, pack two into a uint (lo = first element)
__device__ inline unsigned pk_bf16(float x, float y) {
    unsigned a = __float_as_uint(x) + 0x8000u;
    unsigned b = __float_as_uint(y) + 0x8000u;
    return (a >> 16) | (b & 0xFFFF0000u);
}

// ---------------- embedding + positional encoding ----------------
__global__ __launch_bounds__(256) void embed_kernel(const int* __restrict__ X,
                                                    const float* __restrict__ emb,
                                                    float* __restrict__ h)
{
    int token = blockIdx.x;
    int s = token % SEQ;
    int tid = threadIdx.x;
    int xv = X[token];
    const float* erow = emb + (size_t)xv * DMODEL;
    float* hrow = h + (size_t)token * DMODEL;
#pragma unroll
    for (int i = 0; i < 4; i++) {
        int d = tid + i * 256;
        float j = (float)(d & ~1);
        float invf = expf(j * (-9.210340371976184f / 1024.0f));
        float ang = (float)s * invf;
        float p = (d & 1) ? cosf(ang) : sinf(ang);
        hrow[d] = erow[d] * 32.0f + p;
    }
}

// ------------- generic batched bf16-MFMA GEMM, fp32 in/out -----------------
// C[z] = A[z](MxK) @ B[z](KxN) (+bias)(+relu).  M%128==0, K%64==0.
// BT: B given as [n][k] rows (e.g. K-matrix for Q@K^T).  NG: guard N.
// batch offsets: base + s?b*(z/H) + s?h*(z%H)
template<bool BT, bool NG, bool BIAS, bool RELU>
__global__ __launch_bounds__(256) void bgemm(
    const float* __restrict__ A, int lda, size_t sAb, size_t sAh,
    const float* __restrict__ B, int ldb, size_t sBb, size_t sBh,
    const float* __restrict__ bias,
    float* __restrict__ C, int ldc, size_t sCb, size_t sCh,
    int M, int N, int K, int H)
{
    __shared__ unsigned As[128 * 32];   // 128 rows x 64 bf16 (swizzled 16B granules)
    __shared__ unsigned Bs[128 * 32];

    int tid = threadIdx.x;
    int z = blockIdx.z;
    int zb = z / H, zh = z % H;
    A += sAb * zb + sAh * zh;
    B += sBb * zb + sBh * zh;
    C += sCb * zb + sCh * zh;

    int n0 = blockIdx.x * 128;
    int m0 = blockIdx.y * 128;

    int wv = tid >> 6, lane = tid & 63;
    int wm = (wv >> 1) << 6;        // wave m-offset (0/64)
    int wn = (wv & 1) << 6;         // wave n-offset (0/64)
    int l = lane & 15, kg = lane >> 4;

    int arq = tid >> 3, akq = tid & 7;   // row-major stager: 4 rows, one 8-k granule
    int bk8 = tid >> 5, bng = tid & 31;  // [k][n] stager: 8 k-rows, 4 n-cols

    f32x4 acc[4][4];
#pragma unroll
    for (int i = 0; i < 4; i++)
#pragma unroll
        for (int j = 0; j < 4; j++)
            acc[i][j] = (f32x4){0.f, 0.f, 0.f, 0.f};

    for (int k0 = 0; k0 < K; k0 += 64) {
        // ---- stage A: global [m][k] -> LDS [m][k] ----
        {
            const float* gp = A + (size_t)(m0 + arq * 4) * lda + k0 + akq * 8;
#pragma unroll
            for (int i = 0; i < 4; i++) {
                int r = arq * 4 + i;
                float4 f0 = *(const float4*)(gp + (size_t)i * lda);
                float4 f1 = *(const float4*)(gp + (size_t)i * lda + 4);
                uint4 gr = make_uint4(pk_bf16(f0.x, f0.y), pk_bf16(f0.z, f0.w),
                                      pk_bf16(f1.x, f1.y), pk_bf16(f1.z, f1.w));
                *(uint4*)&As[(r << 5) + ((akq ^ (r & 7)) << 2)] = gr;
            }
        }
        // ---- stage B ----
        if (BT) {
            const float* gp = B + (size_t)(n0 + arq * 4) * ldb + k0 + akq * 8;
#pragma unroll
            for (int i = 0; i < 4; i++) {
                int r = arq * 4 + i;
                uint4 gr;
                if (!NG || (n0 + r) < N) {
                    float4 f0 = *(const float4*)(gp + (size_t)i * ldb);
                    float4 f1 = *(const float4*)(gp + (size_t)i * ldb + 4);
                    gr = make_uint4(pk_bf16(f0.x, f0.y), pk_bf16(f0.z, f0.w),
                                    pk_bf16(f1.x, f1.y), pk_bf16(f1.z, f1.w));
                } else {
                    gr = make_uint4(0u, 0u, 0u, 0u);
                }
                *(uint4*)&Bs[(r << 5) + ((akq ^ (r & 7)) << 2)] = gr;
            }
        } else {
            const float* gp = B + (size_t)(k0 + bk8 * 8) * ldb + n0 + bng * 4;
            bool ok = !NG || (n0 + bng * 4) < N;
            float4 rr[8];
#pragma unroll
            for (int i = 0; i < 8; i++)
                rr[i] = ok ? *(const float4*)(gp + (size_t)i * ldb)
                           : make_float4(0.f, 0.f, 0.f, 0.f);
#define PUTJ(j, comp)                                                          \
            {                                                                  \
                int r = bng * 4 + j;                                           \
                uint4 gr = make_uint4(pk_bf16(rr[0].comp, rr[1].comp),         \
                                      pk_bf16(rr[2].comp, rr[3].comp),         \
                                      pk_bf16(rr[4].comp, rr[5].comp),         \
                                      pk_bf16(rr[6].comp, rr[7].comp));        \
                *(uint4*)&Bs[(r << 5) + ((bk8 ^ (r & 7)) << 2)] = gr;          \
            }
            PUTJ(0, x) PUTJ(1, y) PUTJ(2, z) PUTJ(3, w)
#undef PUTJ
        }
        __syncthreads();

#pragma unroll
        for (int ks = 0; ks < 2; ks++) {
            int g = ks * 4 + kg;
            bf16x8 af[4], bfr[4];
#pragma unroll
            for (int i = 0; i < 4; i++) {
                int r = wm + i * 16 + l;
                af[i] = *(const bf16x8*)&As[(r << 5) + ((g ^ (r & 7)) << 2)];
            }
#pragma unroll
            for (int j = 0; j < 4; j++) {
                int r = wn + j * 16 + l;
                bfr[j] = *(const bf16x8*)&Bs[(r << 5) + ((g ^ (r & 7)) << 2)];
            }
#pragma unroll
            for (int i = 0; i < 4; i++)
#pragma unroll
                for (int j = 0; j < 4; j++)
                    acc[i][j] = __builtin_amdgcn_mfma_f32_16x16x32_bf16(
                        af[i], bfr[j], acc[i][j], 0, 0, 0);
        }
        __syncthreads();
    }

    // ---- epilogue: C/D layout col=lane&15, row=(lane>>4)*4+reg ----
#pragma unroll
    for (int j = 0; j < 4; j++) {
        int col = n0 + wn + j * 16 + l;
        if (NG && col >= N) continue;
        float bv = BIAS ? bias[col] : 0.0f;
#pragma unroll
        for (int i = 0; i < 4; i++) {
            size_t rowb = (size_t)(m0 + wm + i * 16 + (kg << 2));
            float* cp = C + rowb * ldc + col;
#pragma unroll
            for (int r = 0; r < 4; r++) {
                float v = acc[i][j][r] + bv;
                if (RELU) v = fmaxf(v, 0.f);
                cp[(size_t)r * ldc] = v;
            }
        }
    }
}

// ---------------- mask + softmax over S rows (len 256) ---------------------
// S layout: [bh][q][k], bh = b*NHEAD+h. masked (k>=vlim) score = exactly 1e-6.
__global__ __launch_bounds__(256) void softmax_kernel(float* __restrict__ S,
                                                      const int* __restrict__ valid,
                                                      int per_query)
{
    int w = threadIdx.x >> 6, lane = threadIdx.x & 63;
    int q = blockIdx.x * 4 + w;
    int bh = blockIdx.y;
    int b = bh >> 4;
    float* row = S + ((size_t)bh * SEQ + q) * SEQ;
    int vl = valid[b];
    int vlim = per_query ? min(vl, q + 1) : vl;

    int k = lane * 4;
    float4 s = *(float4*)(row + k);
    s.x = (k + 0 >= vlim) ? 1e-6f : s.x * 0.125f;
    s.y = (k + 1 >= vlim) ? 1e-6f : s.y * 0.125f;
    s.z = (k + 2 >= vlim) ? 1e-6f : s.z * 0.125f;
    s.w = (k + 3 >= vlim) ? 1e-6f : s.w * 0.125f;

    float m = fmaxf(fmaxf(s.x, s.y), fmaxf(s.z, s.w));
#pragma unroll
    for (int off = 32; off > 0; off >>= 1) m = fmaxf(m, __shfl_xor(m, off));
    float e0 = expf(s.x - m), e1 = expf(s.y - m);
    float e2 = expf(s.z - m), e3 = expf(s.w - m);
    float ss = e0 + e1 + e2 + e3;
#pragma unroll
    for (int off = 32; off > 0; off >>= 1) ss += __shfl_xor(ss, off);
    float inv = 1.0f / ss;
    *(float4*)(row + k) = make_float4(e0 * inv, e1 * inv, e2 * inv, e3 * inv);
}

// ---------------- out = LayerNorm(x + r) * g + b ---------------------------
__global__ __launch_bounds__(256) void add_ln_kernel(const float* __restrict__ x,
                                                     const float* __restrict__ r,
                                                     const float* __restrict__ g,
                                                     const float* __restrict__ bb,
                                                     float* __restrict__ out)
{
    int row = blockIdx.x;
    int tid = threadIdx.x;
    const float* xr = x + (size_t)row * DMODEL;
    const float* rr = r + (size_t)row * DMODEL;
    float v[4];
#pragma unroll
    for (int i = 0; i < 4; i++) v[i] = xr[tid + i * 256] + rr[tid + i * 256];

    __shared__ float red[4];
    float s = v[0] + v[1] + v[2] + v[3];
#pragma unroll
    for (int off = 32; off > 0; off >>= 1) s += __shfl_xor(s, off);
    int wid = tid >> 6, lane = tid & 63;
    if (lane == 0) red[wid] = s;
    __syncthreads();
    float mean = (red[0] + red[1] + red[2] + red[3]) * (1.0f / DMODEL);

    float sq = 0.f;
#pragma unroll
    for (int i = 0; i < 4; i++) { float d = v[i] - mean; sq = fmaf(d, d, sq); }
    __syncthreads();
#pragma unroll
    for (int off = 32; off > 0; off >>= 1) sq += __shfl_xor(sq, off);
    if (lane == 0) red[wid] = sq;
    __syncthreads();
    float var = (red[0] + red[1] + red[2] + red[3]) * (1.0f / DMODEL);
    float inv = 1.0f / sqrtf(var + 1e-5f);

    float* orow = out + (size_t)row * DMODEL;
#pragma unroll
    for (int i = 0; i < 4; i++) {
        int d = tid + i * 256;
        orow[d] = (v[i] - mean) * inv * g[d] + bb[d];
    }
}

// ---------------------------------------------------------------------------
extern "C" void kernel_launch(void* const* d_in, const int* in_sizes, int n_in,
                              void* d_out, int out_size, void* d_ws, size_t ws_size,
                              hipStream_t stream)
{
    const int*   X         = (const int*)  d_in[0];
    const int*   dec_valid = (const int*)  d_in[1];
    const float* enc       = (const float*)d_in[2];
    const int*   enc_valid = (const int*)  d_in[3];
    const float* emb       = (const float*)d_in[4];
    const float* Wq1  = (const float*)d_in[5];
    const float* Wk1  = (const float*)d_in[6];
    const float* Wv1  = (const float*)d_in[7];
    const float* Wo1  = (const float*)d_in[8];
    const float* Wq2  = (const float*)d_in[9];
    const float* Wk2  = (const float*)d_in[10];
    const float* Wv2  = (const float*)d_in[11];
    const float* Wo2  = (const float*)d_in[12];
    const float* W1   = (const float*)d_in[13];
    const float* W2   = (const float*)d_in[14];
    const float* Wout = (const float*)d_in[15];
    const float* b1   = (const float*)d_in[16];
    const float* b2   = (const float*)d_in[17];
    const float* bout = (const float*)d_in[18];
    const float* ln1g = (const float*)d_in[19];
    const float* ln1b = (const float*)d_in[20];
    const float* ln2g = (const float*)d_in[21];
    const float* ln2b = (const float*)d_in[22];
    const float* ln3g = (const float*)d_in[23];
    const float* ln3b = (const float*)d_in[24];
    float* out = (float*)d_out;
    float* ws  = (float*)d_ws;

    const int MT = BATCH * SEQ;            // 1024 token rows
    const size_t MB = (size_t)1024 * 1024;
    float* h    = ws;
    float* y    = ws + 1 * MB;
    float* y2   = ws + 2 * MB;
    float* proj = ws + 3 * MB;
    float* q    = ws + 4 * MB;
    float* k    = ws + 5 * MB;
    float* v    = ws + 6 * MB;
    float* att  = ws + 7 * MB;
    float* S    = ws + 8 * MB;             // 64*256*256 = 4M floats
    float* ffn  = ws + 8 * MB;             // aliases S (disjoint lifetime)

    embed_kernel<<<MT, 256, 0, stream>>>(X, emb, h);

    dim3 gdd(DMODEL / 128, MT / 128);      // 8x8
    dim3 ghid(HIDDEN / 128, MT / 128);     // 32x8
    dim3 gvoc(VOCAB / 128, MT / 128);      // 250x8
    dim3 gqk(SEQ / 128, SEQ / 128, BATCH * NHEAD);   // 2x2x64
    dim3 gpv(1, SEQ / 128, BATCH * NHEAD);           // 1x2x64
    dim3 gsm(SEQ / 4, BATCH * NHEAD);                // 64x64

    const size_t sTok = (size_t)SEQ * DMODEL;        // batch stride in token arrays
    const size_t sS_h = (size_t)SEQ * SEQ;           // per-head stride in S
    const size_t sS_b = sS_h * NHEAD;

    for (int l = 0; l < NLAYER; l++) {
        const size_t wdd = (size_t)l * DMODEL * DMODEL;
        const float* lg1 = ln1g + (size_t)l * DMODEL; const float* lb1 = ln1b + (size_t)l * DMODEL;
        const float* lg2 = ln2g + (size_t)l * DMODEL; const float* lb2 = ln2b + (size_t)l * DMODEL;
        const float* lg3 = ln3g + (size_t)l * DMODEL; const float* lb3 = ln3b + (size_t)l * DMODEL;

        // ---- self attention ----
        bgemm<false,false,false,false><<<gdd, 256, 0, stream>>>(
            h, DMODEL, 0, 0, Wq1 + wdd, DMODEL, 0, 0, nullptr,
            q, DMODEL, 0, 0, MT, DMODEL, DMODEL, 1);
        bgemm<false,false,false,false><<<gdd, 256, 0, stream>>>(
            h, DMODEL, 0, 0, Wk1 + wdd, DMODEL, 0, 0, nullptr,
            k, DMODEL, 0, 0, MT, DMODEL, DMODEL, 1);
        bgemm<false,false,false,false><<<gdd, 256, 0, stream>>>(
            h, DMODEL, 0, 0, Wv1 + wdd, DMODEL, 0, 0, nullptr,
            v, DMODEL, 0, 0, MT, DMODEL, DMODEL, 1);
        bgemm<true,false,false,false><<<gqk, 256, 0, stream>>>(
            q, DMODEL, sTok, DHEAD, k, DMODEL, sTok, DHEAD, nullptr,
            S, SEQ, sS_b, sS_h, SEQ, SEQ, DHEAD, NHEAD);
        softmax_kernel<<<gsm, 256, 0, stream>>>(S, dec_valid, 1);
        bgemm<false,true,false,false><<<gpv, 256, 0, stream>>>(
            S, SEQ, sS_b, sS_h, v, DMODEL, sTok, DHEAD, nullptr,
            att, DMODEL, sTok, DHEAD, SEQ, DHEAD, SEQ, NHEAD);
        bgemm<false,false,false,false><<<gdd, 256, 0, stream>>>(
            att, DMODEL, 0, 0, Wo1 + wdd, DMODEL, 0, 0, nullptr,
            proj, DMODEL, 0, 0, MT, DMODEL, DMODEL, 1);
        add_ln_kernel<<<MT, 256, 0, stream>>>(h, proj, lg1, lb1, y);

        // ---- cross attention ----
        bgemm<false,false,false,false><<<gdd, 256, 0, stream>>>(
            y, DMODEL, 0, 0, Wq2 + wdd, DMODEL, 0, 0, nullptr,
            q, DMODEL, 0, 0, MT, DMODEL, DMODEL, 1);
        bgemm<false,false,false,false><<<gdd, 256, 0, stream>>>(
            enc, DMODEL, 0, 0, Wk2 + wdd, DMODEL, 0, 0, nullptr,
            k, DMODEL, 0, 0, MT, DMODEL, DMODEL, 1);
        bgemm<false,false,false,false><<<gdd, 256, 0, stream>>>(
            enc, DMODEL, 0, 0, Wv2 + wdd, DMODEL, 0, 0, nullptr,
            v, DMODEL, 0, 0, MT, DMODEL, DMODEL, 1);
        bgemm<true,false,false,false><<<gqk, 256, 0, stream>>>(
            q, DMODEL, sTok, DHEAD, k, DMODEL, sTok, DHEAD, nullptr,
            S, SEQ, sS_b, sS_h, SEQ, SEQ, DHEAD, NHEAD);
        softmax_kernel<<<gsm, 256, 0, stream>>>(S, enc_valid, 0);
        bgemm<false,true,false,false><<<gpv, 256, 0, stream>>>(
            S, SEQ, sS_b, sS_h, v, DMODEL, sTok, DHEAD, nullptr,
            att, DMODEL, sTok, DHEAD, SEQ, DHEAD, SEQ, NHEAD);
        bgemm<false,false,false,false><<<gdd, 256, 0, stream>>>(
            att, DMODEL, 0, 0, Wo2 + wdd, DMODEL, 0, 0, nullptr,
            proj, DMODEL, 0, 0, MT, DMODEL, DMODEL, 1);
        add_ln_kernel<<<MT, 256, 0, stream>>>(y, proj, lg2, lb2, y2);

        // ---- FFN ----
        bgemm<false,false,true,true><<<ghid, 256, 0, stream>>>(
            y2, DMODEL, 0, 0, W1 + (size_t)l * DMODEL * HIDDEN, HIDDEN, 0, 0,
            b1 + (size_t)l * HIDDEN,
            ffn, HIDDEN, 0, 0, MT, HIDDEN, DMODEL, 1);
        bgemm<false,false,true,false><<<gdd, 256, 0, stream>>>(
            ffn, HIDDEN, 0, 0, W2 + (size_t)l * HIDDEN * DMODEL, DMODEL, 0, 0,
            b2 + (size_t)l * DMODEL,
            proj, DMODEL, 0, 0, MT, DMODEL, HIDDEN, 1);
        add_ln_kernel<<<MT, 256, 0, stream>>>(y2, proj, lg3, lb3, h);
    }

    // ---- final projection ----
    bgemm<false,false,true,false><<<gvoc, 256, 0, stream>>>(
        h, DMODEL, 0, 0, Wout, VOCAB, 0, 0, bout,
        out, VOCAB, 0, 0, MT, VOCAB, DMODEL, 1);
}